// Round 4
// baseline (1599.058 us; speedup 1.0000x reference)
//
#include <hip/hip_runtime.h>
#include <stdint.h>

#define D_IN 256
#define D_OUT 128
#define MAXB 800   // max dst-buckets of 128 nodes (N <= 102400)
#define NCHUNK 512

typedef __attribute__((ext_vector_type(8))) short bf16x8;
typedef __attribute__((ext_vector_type(4))) float f32x4;

__device__ __forceinline__ unsigned short f2bf(float f) {
  union { float f; uint32_t u; } v; v.f = f;
  uint32_t u = v.u;
  uint32_t r = (u + 0x7FFFu + ((u >> 16) & 1u)) >> 16;  // RNE
  return (unsigned short)r;
}
__device__ __forceinline__ float bf_lo(uint32_t u) {
  union { uint32_t u; float f; } v; v.u = u << 16; return v.f;
}
__device__ __forceinline__ float bf_hi(uint32_t u) {
  union { uint32_t u; float f; } v; v.u = u & 0xFFFF0000u; return v.f;
}

// W[k][n] (256x128 fp32) -> WT[n][k] (128x256 bf16): B-fragments 16B-contiguous.
__global__ __launch_bounds__(256) void k_conv_w(const float* __restrict__ W,
                                                unsigned short* __restrict__ wt) {
  int idx = blockIdx.x * 256 + threadIdx.x;  // 32768
  int n = idx >> 8;
  int k = idx & 255;
  wt[idx] = f2bf(W[k * D_OUT + n]);
}

// h = x@W (unscaled), fp32 x cvt->bf16 in-register, MFMA 16x16x32 bf16, bf16 store.
// Verified layout (R2): A[m=lane&15][k=q*8+j], B rows = WT[n][k], D col=lane&15 row=q*4+reg.
__global__ __launch_bounds__(256) void k_gemm(const float* __restrict__ x,
                                              const unsigned short* __restrict__ wt,
                                              unsigned short* __restrict__ hp, int N) {
  int wave = threadIdx.x >> 6;
  int lane = threadIdx.x & 63;
  int m = lane & 15;
  int q = lane >> 4;
  int r0 = blockIdx.x * 64 + wave * 16;
  if (r0 >= N) return;  // N % 16 == 0

  bf16x8 a[8];
  const float* xrow = x + (size_t)(r0 + m) * D_IN + q * 8;
#pragma unroll
  for (int kt = 0; kt < 8; ++kt) {
    float4 u0 = *reinterpret_cast<const float4*>(xrow + kt * 32);
    float4 u1 = *reinterpret_cast<const float4*>(xrow + kt * 32 + 4);
    bf16x8 av;
    av[0] = (short)f2bf(u0.x); av[1] = (short)f2bf(u0.y);
    av[2] = (short)f2bf(u0.z); av[3] = (short)f2bf(u0.w);
    av[4] = (short)f2bf(u1.x); av[5] = (short)f2bf(u1.y);
    av[6] = (short)f2bf(u1.z); av[7] = (short)f2bf(u1.w);
    a[kt] = av;
  }

#pragma unroll
  for (int nt = 0; nt < 8; ++nt) {
    f32x4 acc = {0.f, 0.f, 0.f, 0.f};
    const unsigned short* wrow = wt + (size_t)(nt * 16 + m) * D_IN + q * 8;
#pragma unroll
    for (int kt = 0; kt < 8; ++kt) {
      bf16x8 bv = *reinterpret_cast<const bf16x8*>(wrow + kt * 32);
      acc = __builtin_amdgcn_mfma_f32_16x16x32_bf16(a[kt], bv, acc, 0, 0, 0);
    }
#pragma unroll
    for (int r = 0; r < 4; ++r) {
      int row = r0 + q * 4 + r;
      hp[(size_t)row * D_OUT + nt * 16 + m] = f2bf(acc[r]);
    }
  }
}

// passA: per-chunk LDS histogram over dst-buckets -> cntm[b][c]. No global atomics.
__global__ __launch_bounds__(256) void k_passA(const int* __restrict__ ei, int E, int CH,
                                               int NB, int* __restrict__ cntm) {
  __shared__ int bins[MAXB];
  int c = blockIdx.x;
  for (int b = threadIdx.x; b < NB; b += 256) bins[b] = 0;
  __syncthreads();
  int start = c * CH, end = min(E, start + CH);
  for (int e = start + threadIdx.x; e < end; e += 256) {
    int d = ei[E + e];
    atomicAdd(&bins[d >> 7], 1);
  }
  __syncthreads();
  for (int b = threadIdx.x; b < NB; b += 256) cntm[(size_t)b * NCHUNK + c] = bins[b];
}

// scanB1: per bucket, exclusive scan of its 512 chunk counts -> ofs[b][c], tot[b].
__global__ __launch_bounds__(256) void k_scanB1(const int* __restrict__ cntm,
                                                int* __restrict__ ofs,
                                                int* __restrict__ tot) {
  __shared__ int sc[256];
  int b = blockIdx.x;
  int t = threadIdx.x;
  const int* row = cntm + (size_t)b * NCHUNK;
  int v0 = row[2 * t], v1 = row[2 * t + 1];
  int s = v0 + v1;
  sc[t] = s;
  __syncthreads();
  for (int off = 1; off < 256; off <<= 1) {
    int val = (t >= off) ? sc[t - off] : 0;
    __syncthreads();
    sc[t] += val;
    __syncthreads();
  }
  int ex = sc[t] - s;  // exclusive prefix of thread sums
  int* orow = ofs + (size_t)b * NCHUNK;
  orow[2 * t] = ex;
  orow[2 * t + 1] = ex + v0;
  if (t == 255) tot[b] = sc[255];
}

// scanB2: single block, exclusive scan of bucket totals -> base[b].
__global__ __launch_bounds__(256) void k_scanB2(const int* __restrict__ tot,
                                                int* __restrict__ base, int NB) {
  __shared__ int sc[256];
  int t = threadIdx.x;
  int v[4];
  int s = 0;
#pragma unroll
  for (int j = 0; j < 4; ++j) {
    int i = t * 4 + j;
    v[j] = (i < NB) ? tot[i] : 0;
    s += v[j];
  }
  sc[t] = s;
  __syncthreads();
  for (int off = 1; off < 256; off <<= 1) {
    int val = (t >= off) ? sc[t - off] : 0;
    __syncthreads();
    sc[t] += val;
    __syncthreads();
  }
  int ex = sc[t] - s;
#pragma unroll
  for (int j = 0; j < 4; ++j) {
    int i = t * 4 + j;
    if (i < NB) base[i] = ex;
    ex += v[j];
  }
}

// passC: place each edge at its arithmetically-determined slot. LDS cursors only.
// P entry = src | (dst&127)<<17   (src < 2^17)
__global__ __launch_bounds__(256) void k_passC(const int* __restrict__ ei, int E, int CH,
                                               int NB, const int* __restrict__ ofs,
                                               const int* __restrict__ base,
                                               int* __restrict__ P) {
  __shared__ int cur[MAXB];
  int c = blockIdx.x;
  for (int b = threadIdx.x; b < NB; b += 256)
    cur[b] = base[b] + ofs[(size_t)b * NCHUNK + c];
  __syncthreads();
  int start = c * CH, end = min(E, start + CH);
  for (int e = start + threadIdx.x; e < end; e += 256) {
    int s = ei[e];
    int d = ei[E + e];
    int b = d >> 7;
    int p = atomicAdd(&cur[b], 1);  // LDS returning atomic — fast
    P[p] = s | ((d & 127) << 17);
  }
}

// dinv: per bucket LDS degree hist; bucket owns nodes [128b,128b+128) -> plain stores.
__global__ __launch_bounds__(256) void k_dinv(const int* __restrict__ P,
                                              const int* __restrict__ base,
                                              const int* __restrict__ tot,
                                              float* __restrict__ dinv, int N) {
  __shared__ int ideg[128];
  int b = blockIdx.x;
  if (threadIdx.x < 128) ideg[threadIdx.x] = 0;
  __syncthreads();
  int s0 = base[b], e0 = s0 + tot[b];
  for (int i = s0 + threadIdx.x; i < e0; i += 256) atomicAdd(&ideg[P[i] >> 17], 1);
  __syncthreads();
  int node = b * 128 + threadIdx.x;
  if (threadIdx.x < 128 && node < N)
    dinv[node] = rsqrtf(1.0f + (float)ideg[threadIdx.x]);
}

// agg: one block per bucket; 128x128 fp32 accumulator in LDS; 8-deep gather ILP;
// ds_add_f32 accumulation; coalesced epilogue with self term + dinv^2 + bias + relu.
__global__ __launch_bounds__(256, 2) void k_agg(const int* __restrict__ P,
                                                const int* __restrict__ base,
                                                const int* __restrict__ tot,
                                                const uint32_t* __restrict__ hp32,
                                                const float* __restrict__ dinv,
                                                const float* __restrict__ bias,
                                                float* __restrict__ out, int N) {
  __shared__ float acc[128 * 128];
  int b = blockIdx.x;
  float4* a4 = (float4*)acc;
  for (int i = threadIdx.x; i < 128 * 128 / 4; i += 256)
    a4[i] = float4{0.f, 0.f, 0.f, 0.f};
  __syncthreads();

  int T = tot[b];
  int B0 = base[b];
  int wave = threadIdx.x >> 6, lane = threadIdx.x & 63;
  int ws = B0 + (int)(((long long)T * wave) >> 2);
  int we = B0 + (int)(((long long)T * (wave + 1)) >> 2);

  int e = ws;
  for (; e + 8 <= we; e += 8) {
    int pk[8];
    uint32_t u[8];
    float r[8];
#pragma unroll
    for (int j = 0; j < 8; ++j) pk[j] = P[e + j];
#pragma unroll
    for (int j = 0; j < 8; ++j)
      u[j] = hp32[(size_t)(pk[j] & 0x1FFFF) * 64 + lane];
#pragma unroll
    for (int j = 0; j < 8; ++j) r[j] = dinv[pk[j] & 0x1FFFF];
#pragma unroll
    for (int j = 0; j < 8; ++j) {
      int dl = pk[j] >> 17;
      float* row = acc + dl * 128 + 2 * lane;
      atomicAdd(row, r[j] * bf_lo(u[j]));
      atomicAdd(row + 1, r[j] * bf_hi(u[j]));
    }
  }
  for (; e < we; ++e) {
    int pk = P[e];
    uint32_t u = hp32[(size_t)(pk & 0x1FFFF) * 64 + lane];
    float r = dinv[pk & 0x1FFFF];
    int dl = pk >> 17;
    atomicAdd(acc + dl * 128 + 2 * lane, r * bf_lo(u));
    atomicAdd(acc + dl * 128 + 2 * lane + 1, r * bf_hi(u));
  }
  __syncthreads();

  for (int i = threadIdx.x; i < 128 * 128; i += 256) {
    int nl = i >> 7, col = i & 127;
    int node = b * 128 + nl;
    if (node < N) {
      float rs = dinv[node];
      uint32_t uh = hp32[(size_t)node * 64 + (col >> 1)];
      float self = (col & 1) ? bf_hi(uh) : bf_lo(uh);
      float v = rs * (acc[i] + rs * self) + bias[col];
      out[(size_t)node * D_OUT + col] = v > 0.f ? v : 0.f;
    }
  }
}

extern "C" void kernel_launch(void* const* d_in, const int* in_sizes, int n_in,
                              void* d_out, int out_size, void* d_ws, size_t ws_size,
                              hipStream_t stream) {
  const float* x = (const float*)d_in[0];
  const int* ei = (const int*)d_in[1];
  const float* W = (const float*)d_in[2];
  const float* bias = (const float*)d_in[3];
  int N = in_sizes[0] / D_IN;
  int E = in_sizes[1] / 2;
  float* out = (float*)d_out;

  int NB = (N + 127) >> 7;              // 782 dst-buckets
  int CH = (E + NCHUNK - 1) / NCHUNK;   // 3125 edges/chunk

  // Workspace (~36 MB): wt | hp | dinv | cntm | ofs | tot | base | P
  char* w = (char*)d_ws;
  size_t off = 0;
  auto alloc = [&](size_t bytes) -> void* {
    void* p = w + off;
    off = (off + bytes + 255) & ~(size_t)255;
    return p;
  };
  unsigned short* wt = (unsigned short*)alloc((size_t)D_IN * D_OUT * 2);
  unsigned short* hp = (unsigned short*)alloc((size_t)N * D_OUT * 2);
  float* dinv = (float*)alloc((size_t)N * 4);
  int* cntm = (int*)alloc((size_t)NB * NCHUNK * 4);
  int* ofs = (int*)alloc((size_t)NB * NCHUNK * 4);
  int* tot = (int*)alloc((size_t)NB * 4);
  int* base = (int*)alloc((size_t)NB * 4);
  int* P = (int*)alloc((size_t)E * 4);
  (void)ws_size; (void)n_in; (void)out_size;

  int Gg = (N + 63) / 64;

  k_conv_w<<<(D_IN * D_OUT) / 256, 256, 0, stream>>>(W, wt);
  k_gemm<<<Gg, 256, 0, stream>>>(x, wt, hp, N);
  k_passA<<<NCHUNK, 256, 0, stream>>>(ei, E, CH, NB, cntm);
  k_scanB1<<<NB, 256, 0, stream>>>(cntm, ofs, tot);
  k_scanB2<<<1, 256, 0, stream>>>(tot, base, NB);
  k_passC<<<NCHUNK, 256, 0, stream>>>(ei, E, CH, NB, ofs, base, P);
  k_dinv<<<NB, 256, 0, stream>>>(P, base, tot, dinv, N);
  k_agg<<<NB, 256, 0, stream>>>(P, base, tot, (const uint32_t*)hp, dinv, bias, out, N);
}

// Round 5
// 327.450 us; speedup vs baseline: 4.8834x; 4.8834x over previous
//
#include <hip/hip_runtime.h>
#include <stdint.h>

#define D_IN 256
#define D_OUT 128
#define MAXB 800     // max dst-buckets of 128 nodes (N <= 102400)
#define NCHUNK 256   // edge chunks (blocks) for partition passes

typedef __attribute__((ext_vector_type(8))) short bf16x8;
typedef __attribute__((ext_vector_type(4))) float f32x4;

__device__ __forceinline__ unsigned short f2bf(float f) {
  union { float f; uint32_t u; } v; v.f = f;
  uint32_t u = v.u;
  uint32_t r = (u + 0x7FFFu + ((u >> 16) & 1u)) >> 16;  // RNE
  return (unsigned short)r;
}
__device__ __forceinline__ float bf_lo(uint32_t u) {
  union { uint32_t u; float f; } v; v.u = u << 16; return v.f;
}
__device__ __forceinline__ float bf_hi(uint32_t u) {
  union { uint32_t u; float f; } v; v.u = u & 0xFFFF0000u; return v.f;
}

// W[k][n] (256x128 fp32) -> WT[n][k] (128x256 bf16): B-fragments 16B-contiguous.
__global__ __launch_bounds__(256) void k_conv_w(const float* __restrict__ W,
                                                unsigned short* __restrict__ wt) {
  int idx = blockIdx.x * 256 + threadIdx.x;  // 32768
  int n = idx >> 8;
  int k = idx & 255;
  wt[idx] = f2bf(W[k * D_OUT + n]);
}

// h = x@W (unscaled), fp32 x cvt->bf16 in-register, MFMA 16x16x32 bf16, bf16 store.
__global__ __launch_bounds__(256) void k_gemm(const float* __restrict__ x,
                                              const unsigned short* __restrict__ wt,
                                              unsigned short* __restrict__ hp, int N) {
  int wave = threadIdx.x >> 6;
  int lane = threadIdx.x & 63;
  int m = lane & 15;
  int q = lane >> 4;
  int r0 = blockIdx.x * 64 + wave * 16;
  if (r0 >= N) return;  // N % 16 == 0

  bf16x8 a[8];
  const float* xrow = x + (size_t)(r0 + m) * D_IN + q * 8;
#pragma unroll
  for (int kt = 0; kt < 8; ++kt) {
    float4 u0 = *reinterpret_cast<const float4*>(xrow + kt * 32);
    float4 u1 = *reinterpret_cast<const float4*>(xrow + kt * 32 + 4);
    bf16x8 av;
    av[0] = (short)f2bf(u0.x); av[1] = (short)f2bf(u0.y);
    av[2] = (short)f2bf(u0.z); av[3] = (short)f2bf(u0.w);
    av[4] = (short)f2bf(u1.x); av[5] = (short)f2bf(u1.y);
    av[6] = (short)f2bf(u1.z); av[7] = (short)f2bf(u1.w);
    a[kt] = av;
  }

#pragma unroll
  for (int nt = 0; nt < 8; ++nt) {
    f32x4 acc = {0.f, 0.f, 0.f, 0.f};
    const unsigned short* wrow = wt + (size_t)(nt * 16 + m) * D_IN + q * 8;
#pragma unroll
    for (int kt = 0; kt < 8; ++kt) {
      bf16x8 bv = *reinterpret_cast<const bf16x8*>(wrow + kt * 32);
      acc = __builtin_amdgcn_mfma_f32_16x16x32_bf16(a[kt], bv, acc, 0, 0, 0);
    }
#pragma unroll
    for (int r = 0; r < 4; ++r) {
      int row = r0 + q * 4 + r;
      hp[(size_t)row * D_OUT + nt * 16 + m] = f2bf(acc[r]);
    }
  }
}

// passA: per-chunk LDS histogram over dst-buckets -> cntm[b][c]. LDS atomics only.
__global__ __launch_bounds__(256) void k_passA(const int* __restrict__ ei, int E, int CH,
                                               int NB, int* __restrict__ cntm) {
  __shared__ int bins[MAXB];
  int c = blockIdx.x;
  for (int b = threadIdx.x; b < NB; b += 256) bins[b] = 0;
  __syncthreads();
  int start = c * CH, end = min(E, start + CH);
  for (int eb = start + (int)threadIdx.x * 4; eb < end; eb += 1024) {
    int kmax = end - eb; if (kmax > 4) kmax = 4;
    if (kmax == 4) {
      int4 v = *reinterpret_cast<const int4*>(ei + E + eb);
      atomicAdd(&bins[v.x >> 7], 1);
      atomicAdd(&bins[v.y >> 7], 1);
      atomicAdd(&bins[v.z >> 7], 1);
      atomicAdd(&bins[v.w >> 7], 1);
    } else {
      for (int k = 0; k < kmax; ++k) atomicAdd(&bins[ei[E + eb + k] >> 7], 1);
    }
  }
  __syncthreads();
  for (int b = threadIdx.x; b < NB; b += 256) cntm[(size_t)b * NCHUNK + c] = bins[b];
}

// scanB1: per bucket, exclusive scan of its NCHUNK chunk counts -> ofs, tot.
__global__ __launch_bounds__(NCHUNK) void k_scanB1(const int* __restrict__ cntm,
                                                   int* __restrict__ ofs,
                                                   int* __restrict__ tot) {
  __shared__ int sc[NCHUNK];
  int b = blockIdx.x, t = threadIdx.x;
  int v = cntm[(size_t)b * NCHUNK + t];
  sc[t] = v;
  __syncthreads();
  for (int off = 1; off < NCHUNK; off <<= 1) {
    int val = (t >= off) ? sc[t - off] : 0;
    __syncthreads();
    sc[t] += val;
    __syncthreads();
  }
  ofs[(size_t)b * NCHUNK + t] = sc[t] - v;
  if (t == NCHUNK - 1) tot[b] = sc[t];
}

// scanB2: single block, exclusive scan of bucket totals -> base[b]. Also nptr[N]=E.
__global__ __launch_bounds__(256) void k_scanB2(const int* __restrict__ tot,
                                                int* __restrict__ base, int NB,
                                                int* __restrict__ nptr, int N, int E) {
  __shared__ int sc[256];
  int t = threadIdx.x;
  int v[4];
  int s = 0;
#pragma unroll
  for (int j = 0; j < 4; ++j) {
    int i = t * 4 + j;
    v[j] = (i < NB) ? tot[i] : 0;
    s += v[j];
  }
  sc[t] = s;
  __syncthreads();
  for (int off = 1; off < 256; off <<= 1) {
    int val = (t >= off) ? sc[t - off] : 0;
    __syncthreads();
    sc[t] += val;
    __syncthreads();
  }
  int ex = sc[t] - s;
#pragma unroll
  for (int j = 0; j < 4; ++j) {
    int i = t * 4 + j;
    if (i < NB) base[i] = ex;
    ex += v[j];
  }
  if (t == 0) nptr[N] = E;
}

// passC: place each edge in its bucket's span. LDS cursors only.
// P entry = src | (dst&127)<<17   (src < 2^17)
__global__ __launch_bounds__(256) void k_passC(const int* __restrict__ ei, int E, int CH,
                                               int NB, const int* __restrict__ ofs,
                                               const int* __restrict__ base,
                                               int* __restrict__ P) {
  __shared__ int cur[MAXB];
  int c = blockIdx.x;
  for (int b = threadIdx.x; b < NB; b += 256)
    cur[b] = base[b] + ofs[(size_t)b * NCHUNK + c];
  __syncthreads();
  int start = c * CH, end = min(E, start + CH);
  for (int eb = start + (int)threadIdx.x * 4; eb < end; eb += 1024) {
    int kmax = end - eb; if (kmax > 4) kmax = 4;
    int s4[4], d4[4];
    if (kmax == 4) {
      int4 vs = *reinterpret_cast<const int4*>(ei + eb);
      int4 vd = *reinterpret_cast<const int4*>(ei + E + eb);
      s4[0] = vs.x; s4[1] = vs.y; s4[2] = vs.z; s4[3] = vs.w;
      d4[0] = vd.x; d4[1] = vd.y; d4[2] = vd.z; d4[3] = vd.w;
    } else {
      for (int k = 0; k < kmax; ++k) { s4[k] = ei[eb + k]; d4[k] = ei[E + eb + k]; }
    }
#pragma unroll
    for (int k = 0; k < 4; ++k) {
      if (k >= kmax) break;
      int d = d4[k];
      int p = atomicAdd(&cur[d >> 7], 1);
      P[p] = s4[k] | ((d & 127) << 17);
    }
  }
}

// sortd: per bucket counting-sort by dst-low -> P2 (globally dst-sorted CSR),
// nptr[node], dinv[node]. LDS only; no global atomics.
__global__ __launch_bounds__(256) void k_sortd(const int* __restrict__ P,
                                               const int* __restrict__ base,
                                               const int* __restrict__ tot,
                                               int* __restrict__ nptr,
                                               float* __restrict__ dinv,
                                               int* __restrict__ P2, int N) {
  __shared__ int ideg[128];
  __shared__ int sc[128];
  __shared__ int cur[128];
  int b = blockIdx.x, t = threadIdx.x;
  if (t < 128) ideg[t] = 0;
  __syncthreads();
  int s0 = base[b], T = tot[b];
  for (int i = s0 + t; i < s0 + T; i += 256) atomicAdd(&ideg[P[i] >> 17], 1);
  __syncthreads();
  if (t < 128) sc[t] = ideg[t];
  __syncthreads();
  for (int off = 1; off < 128; off <<= 1) {
    int v = (t < 128 && t >= off) ? sc[t - off] : 0;
    __syncthreads();
    if (t < 128) sc[t] += v;
    __syncthreads();
  }
  if (t < 128) {
    int exc = s0 + sc[t] - ideg[t];
    int node = b * 128 + t;
    if (node < N) {
      nptr[node] = exc;
      dinv[node] = rsqrtf(1.0f + (float)ideg[t]);
    }
    cur[t] = exc;
  }
  __syncthreads();
  for (int i = s0 + t; i < s0 + T; i += 256) {
    int pk = P[i];
    int p = atomicAdd(&cur[pk >> 17], 1);
    P2[p] = pk & 0x1FFFF;
  }
}

// agg: one wave per node over its CSR run. 4 edges/iter: lane j=lane>>4 takes edge
// e+j, c=lane&15 covers 8 cols via one dwordx4 (dense 256B row per instr). Register
// accumulate, shfl_xor reduce across edge slots, coalesced fp32 epilogue.
__global__ __launch_bounds__(256) void k_agg(const int* __restrict__ P2,
                                             const int* __restrict__ nptr,
                                             const uint4* __restrict__ hrows,
                                             const float* __restrict__ dinv,
                                             const float* __restrict__ bias,
                                             float* __restrict__ out, int N) {
  int wave = threadIdx.x >> 6, lane = threadIdx.x & 63;
  int node = blockIdx.x * 4 + wave;
  if (node >= N) return;
  int rs = nptr[node], re = nptr[node + 1];
  int j = lane >> 4, c = lane & 15;

  float acc[8];
#pragma unroll
  for (int k = 0; k < 8; ++k) acc[k] = 0.f;

  for (int e = rs + j; e < re; e += 4) {
    int src = P2[e];
    float r = dinv[src];
    uint4 u = hrows[(size_t)src * 16 + c];
    acc[0] += r * bf_lo(u.x); acc[1] += r * bf_hi(u.x);
    acc[2] += r * bf_lo(u.y); acc[3] += r * bf_hi(u.y);
    acc[4] += r * bf_lo(u.z); acc[5] += r * bf_hi(u.z);
    acc[6] += r * bf_lo(u.w); acc[7] += r * bf_hi(u.w);
  }
#pragma unroll
  for (int k = 0; k < 8; ++k) {
    acc[k] += __shfl_xor(acc[k], 16);
    acc[k] += __shfl_xor(acc[k], 32);
  }
  if (j == 0) {
    float rsn = dinv[node];
    uint4 uh = hrows[(size_t)node * 16 + c];
    float self[8] = {bf_lo(uh.x), bf_hi(uh.x), bf_lo(uh.y), bf_hi(uh.y),
                     bf_lo(uh.z), bf_hi(uh.z), bf_lo(uh.w), bf_hi(uh.w)};
    const float4* b4 = reinterpret_cast<const float4*>(bias);
    float4 b0 = b4[c * 2], b1 = b4[c * 2 + 1];
    float bb[8] = {b0.x, b0.y, b0.z, b0.w, b1.x, b1.y, b1.z, b1.w};
    float o[8];
#pragma unroll
    for (int k = 0; k < 8; ++k) {
      float v = rsn * (acc[k] + rsn * self[k]) + bb[k];
      o[k] = v > 0.f ? v : 0.f;
    }
    float4* orow = reinterpret_cast<float4*>(out + (size_t)node * D_OUT + c * 8);
    orow[0] = float4{o[0], o[1], o[2], o[3]};
    orow[1] = float4{o[4], o[5], o[6], o[7]};
  }
}

extern "C" void kernel_launch(void* const* d_in, const int* in_sizes, int n_in,
                              void* d_out, int out_size, void* d_ws, size_t ws_size,
                              hipStream_t stream) {
  const float* x = (const float*)d_in[0];
  const int* ei = (const int*)d_in[1];
  const float* W = (const float*)d_in[2];
  const float* bias = (const float*)d_in[3];
  int N = in_sizes[0] / D_IN;
  int E = in_sizes[1] / 2;
  float* out = (float*)d_out;

  int NB = (N + 127) >> 7;                          // 782 buckets
  int CH = ((E + NCHUNK - 1) / NCHUNK + 3) & ~3;    // 4-aligned for int4 loads

  // Workspace (~41 MB): wt | hp | dinv | cntm | ofs | tot | base | nptr | P | P2
  char* w = (char*)d_ws;
  size_t off = 0;
  auto alloc = [&](size_t bytes) -> void* {
    void* p = w + off;
    off = (off + bytes + 255) & ~(size_t)255;
    return p;
  };
  unsigned short* wt = (unsigned short*)alloc((size_t)D_IN * D_OUT * 2);
  unsigned short* hp = (unsigned short*)alloc((size_t)N * D_OUT * 2);
  float* dinv = (float*)alloc((size_t)N * 4);
  int* cntm = (int*)alloc((size_t)NB * NCHUNK * 4);
  int* ofs = (int*)alloc((size_t)NB * NCHUNK * 4);
  int* tot = (int*)alloc((size_t)NB * 4);
  int* base = (int*)alloc((size_t)NB * 4);
  int* nptr = (int*)alloc((size_t)(N + 1) * 4);
  int* P = (int*)alloc((size_t)E * 4);
  int* P2 = (int*)alloc((size_t)E * 4);
  (void)ws_size; (void)n_in; (void)out_size;

  k_conv_w<<<(D_IN * D_OUT) / 256, 256, 0, stream>>>(W, wt);
  k_gemm<<<(N + 63) / 64, 256, 0, stream>>>(x, wt, hp, N);
  k_passA<<<NCHUNK, 256, 0, stream>>>(ei, E, CH, NB, cntm);
  k_scanB1<<<NB, NCHUNK, 0, stream>>>(cntm, ofs, tot);
  k_scanB2<<<1, 256, 0, stream>>>(tot, base, NB, nptr, N, E);
  k_passC<<<NCHUNK, 256, 0, stream>>>(ei, E, CH, NB, ofs, base, P);
  k_sortd<<<NB, 256, 0, stream>>>(P, base, tot, nptr, dinv, P2, N);
  k_agg<<<(N + 3) / 4, 256, 0, stream>>>(P2, nptr, (const uint4*)hp, dinv, bias, out, N);
}